// Round 1
// baseline (42.363 us; speedup 1.0000x reference)
//
#include <hip/hip_runtime.h>

typedef float f32x4 __attribute__((ext_vector_type(4)));
typedef __bf16 bf16x8 __attribute__((ext_vector_type(8)));

#define K_FEAT 8192
#define N_FEAT 8192
#define M_TOK 64
#define TILES_N 512
#define TILES_K 512
#define WROWSTRIDE 40   /* 32 k + 8 pad, in ushort units */

__device__ __forceinline__ unsigned short f2bf(float f) {
    unsigned int u = __builtin_bit_cast(unsigned int, f);
    u = (u + 0x7FFFu + ((u >> 16) & 1u)) >> 16;
    return (unsigned short)u;
}

// xb[m][k] = bf16(x[m][k] * su[k])
__global__ void __launch_bounds__(256)
prep_x_kernel(const float* __restrict__ x, const float* __restrict__ su,
              unsigned short* __restrict__ xb)
{
    int i = blockIdx.x * 256 + threadIdx.x;          // float4 index over [64][8192]
    const float4* x4 = (const float4*)x;
    const float4* su4 = (const float4*)su;
    float4 xv = x4[i];
    float4 s4 = su4[i & (K_FEAT / 4 - 1)];
    ushort4 o;
    o.x = f2bf(xv.x * s4.x);
    o.y = f2bf(xv.y * s4.y);
    o.z = f2bf(xv.z * s4.z);
    o.w = f2bf(xv.w * s4.w);
    ((ushort4*)xb)[i] = o;
}

__global__ void __launch_bounds__(256)
trellis_main(const int* __restrict__ packed,
             const float* __restrict__ scales,
             const float* __restrict__ sv,
             const float* __restrict__ grid,
             const unsigned short* __restrict__ xb,
             float* __restrict__ partials,
             int lg_ksplit)
{
    __shared__ unsigned int table[256];
    __shared__ unsigned short wlds[2][64 * WROWSTRIDE];

    const int tid = threadIdx.x;
    const int bid = blockIdx.x;
    const int ksplit = 1 << lg_ksplit;
    const int s = bid & (ksplit - 1);
    const int ng = bid >> lg_ksplit;
    const int col0 = ng * 64;
    const int nt0 = ng * 4;
    const int ktile0 = s * (TILES_K >> lg_ksplit);
    const int nstep = (TILES_K >> lg_ksplit) >> 1;   // 2 k-tiles (32 rows) per step

    // ---- staging coordinates: thread covers 8 weights = one n-row x 4 k, twice ----
    const int tau = tid >> 5;        // 8 tiles staged per step (2 kt x 4 nt)
    const int dkt = tau >> 2;        // 0..1
    const int dnt_s = tau & 3;       // 0..3
    const int w = tid & 31;
    const int c = w & 7;             // column pair: n = 2c, 2c+1
    const int g = w >> 3;            // k-group: kk = 4g..4g+3

    const int* pb = packed
        + ((size_t)(ktile0 + dkt) * TILES_N + (nt0 + dnt_s)) * 128 + c + 32 * g;
    const int stepstride = 2 * TILES_N * 128;        // advance tk by 2

    // ---- compute coordinates ----
    const int wave = tid >> 6;       // m-tile
    const int lane = tid & 63;
    const int ln15 = lane & 15;
    const int kgrp = (lane >> 4) * 8;
    const unsigned short* xrow = xb + (size_t)(wave * 16 + ln15) * K_FEAT;

    // pair table: byte -> (bf16(grid[lo]), bf16(grid[hi]))
    {
        float lo = grid[tid & 15];
        float hi = grid[(tid >> 4) & 15];
        table[tid] = (unsigned int)f2bf(lo) | ((unsigned int)f2bf(hi) << 16);
    }

    // prologue: packed ints for step 0, A-frag for step 0
    int ld0 = pb[0], ld1 = pb[8], ld2 = pb[16], ld3 = pb[24];
    uint4 ra = *(const uint4*)(xrow + ktile0 * 16 + kgrp);

    f32x4 acc[4], acc2[4];
    for (int d = 0; d < 4; ++d)
        for (int j = 0; j < 4; ++j) { acc[d][j] = 0.f; acc2[d][j] = 0.f; }

    __syncthreads();   // table ready

    for (int t = 0; t < nstep; ++t) {
        // prefetch next step's packed ints (one full step of latency hiding)
        const int* pn = pb + (size_t)(t + 1 < nstep ? (t + 1) : 0) * stepstride;
        int n0 = pn[0], n1 = pn[8], n2 = pn[16], n3 = pn[24];

        // dequant current step -> wlds[t&1], layout [n][k] (padded rows)
        unsigned int t0 = table[ld0 & 255];
        unsigned int t1 = table[ld1 & 255];
        unsigned int t2 = table[ld2 & 255];
        unsigned int t3 = table[ld3 & 255];
        unsigned int w0 = (t0 & 0xFFFFu) | (t1 << 16);          // row 2c,   k 4g..4g+1
        unsigned int w1 = (t2 & 0xFFFFu) | (t3 << 16);          // row 2c,   k 4g+2..4g+3
        unsigned int w2 = (t0 >> 16)     | (t1 & 0xFFFF0000u);  // row 2c+1
        unsigned int w3 = (t2 >> 16)     | (t3 & 0xFFFF0000u);
        {
            int nrow = dnt_s * 16 + 2 * c;
            int koff = dkt * 16 + 4 * g;
            unsigned short* dst = &wlds[t & 1][nrow * WROWSTRIDE + koff];
            *(uint2*)dst = make_uint2(w0, w1);
            *(uint2*)(dst + WROWSTRIDE) = make_uint2(w2, w3);
        }

        __syncthreads();   // one barrier per step is sufficient (alternating buffers)

        // prefetch next A-fragment
        int k0n = ktile0 * 16 + (t + 1 < nstep ? (t + 1) : 0) * 32;
        uint4 ran = *(const uint4*)(xrow + k0n + kgrp);

        bf16x8 a = __builtin_bit_cast(bf16x8, ra);
        const unsigned short* wbase = &wlds[t & 1][0];
        for (int d = 0; d < 4; ++d) {
            bf16x8 b = *(const bf16x8*)(wbase + (d * 16 + ln15) * WROWSTRIDE + kgrp);
            acc2[d] = __builtin_amdgcn_mfma_f32_16x16x32_bf16(a, b, acc2[d], 0, 0, 0);
        }
        ra = ran;
        ld0 = n0; ld1 = n1; ld2 = n2; ld3 = n3;

        // every 4 steps (= 128 k rows = one scale block): fold scales into acc
        if ((t & 3) == 3) {
            int kb = (ktile0 * 16 + (t & ~3) * 32) >> 7;
            const float* srow = scales + (size_t)kb * N_FEAT + col0 + ln15;
            for (int d = 0; d < 4; ++d) {
                float sc = srow[d * 16];
                acc[d] += acc2[d] * sc;
                for (int j = 0; j < 4; ++j) acc2[d][j] = 0.f;
            }
        }
    }

    // epilogue: apply sv, write partial [s][m][n]
    float* pout = partials + (size_t)s * (M_TOK * N_FEAT);
    const int rbase = (lane >> 4) * 4;
    for (int d = 0; d < 4; ++d) {
        int n = col0 + d * 16 + ln15;
        float svv = sv[n];
        for (int j = 0; j < 4; ++j) {
            int m = wave * 16 + rbase + j;
            pout[(size_t)m * N_FEAT + n] = acc[d][j] * svv;
        }
    }
}

__global__ void __launch_bounds__(256)
reduce_kernel(const float* __restrict__ partials, float* __restrict__ out, int ksplit)
{
    int i = blockIdx.x * 256 + threadIdx.x;          // float4 index, 131072 total
    const float4* p4 = (const float4*)partials;
    float4 a = p4[i];
    for (int k = 1; k < ksplit; ++k) {
        float4 v = p4[(size_t)k * (M_TOK * N_FEAT / 4) + i];
        a.x += v.x; a.y += v.y; a.z += v.z; a.w += v.w;
    }
    ((float4*)out)[i] = a;
}

extern "C" void kernel_launch(void* const* d_in, const int* in_sizes, int n_in,
                              void* d_out, int out_size, void* d_ws, size_t ws_size,
                              hipStream_t stream)
{
    const float* x      = (const float*)d_in[0];
    const int*   packed = (const int*)d_in[1];
    const float* scales = (const float*)d_in[2];
    const float* su     = (const float*)d_in[3];
    const float* sv     = (const float*)d_in[4];
    const float* grid   = (const float*)d_in[5];
    float* out = (float*)d_out;

    unsigned short* xb = (unsigned short*)d_ws;
    const size_t xb_bytes = (size_t)M_TOK * K_FEAT * 2;   // 1 MB
    int lg = 3;
    while (lg > 0 &&
           xb_bytes + ((size_t)(1 << lg)) * M_TOK * N_FEAT * 4 > ws_size) --lg;
    const int ksplit = 1 << lg;
    float* partials = (float*)((char*)d_ws + xb_bytes);

    prep_x_kernel<<<(M_TOK * K_FEAT / 4) / 256, 256, 0, stream>>>(x, su, xb);
    trellis_main<<<(N_FEAT / 64) * ksplit, 256, 0, stream>>>(
        packed, scales, sv, grid, xb, partials, lg);
    reduce_kernel<<<(M_TOK * N_FEAT / 4) / 256, 256, 0, stream>>>(partials, out, ksplit);
}